// Round 4
// baseline (290.311 us; speedup 1.0000x reference)
//
#include <hip/hip_runtime.h>
#include <hip/hip_bf16.h>

typedef __hip_bfloat16 bf16;
typedef __attribute__((ext_vector_type(8))) short s8v;   // 8 bf16 = 4 VGPR (MFMA A/B frag)
typedef __attribute__((ext_vector_type(4))) float f4v;   // MFMA C/D frag

__device__ __forceinline__ ushort f2u(float f) {
    bf16 h = __float2bfloat16(f);
    return *(ushort*)&h;
}

// ---------------------------------------------------------------------------
// B=4, C=256, H=W=64, N=4096. All inputs/outputs fp32; internal bf16.
// ws: cat  bf16 [16384][512]   @ 0          (16 MiB)
//     Qb   bf16 [16384][32]    @ 16777216   ( 1 MiB)
//     Kb   bf16 [16384][32]    @ 17825792   ( 1 MiB)
//     Vt   bf16 [4][256][4096] @ 18874368   ( 8 MiB)
// MFMA 16x16x32 bf16 layouts (m89/m120-verified):
//   A: lane holds A[m=lane&15][k=(lane>>4)*8+j]
//   B: lane holds B[k=(lane>>4)*8+j][n=lane&15]
//   C/D: lane holds D[row=(lane>>4)*4+r][col=lane&15]
// ---------------------------------------------------------------------------

// Kernel 1: 3x3 avg(/9, include-pad) + 3x3 max. LDS-free.
// Thread owns (c, 16-wide w strip); h-contiguous blocks per XCD for L2 reuse.
__global__ __launch_bounds__(256) void pool_kernel(const float* __restrict__ x,
                                                   ushort* __restrict__ cat) {
    int bid = blockIdx.x;
    int g = (bid & 7) * 128 + (bid >> 3);   // per-XCD h-contiguous slices
    int b = g >> 8, h = (g >> 2) & 63, cg = g & 3;
    int s = threadIdx.x >> 6, cl = threadIdx.x & 63;
    int c = cg * 64 + cl;
    const float* xr = x + ((size_t)(b * 256 + c)) * 4096;

    float vs[24], vm[24];
    #pragma unroll
    for (int j = 0; j < 24; ++j) { vs[j] = 0.f; vm[j] = -3.4e38f; }
    #pragma unroll
    for (int dh = 0; dh < 3; ++dh) {
        int hh = h + dh - 1;
        if ((unsigned)hh < 64u) {                 // block-uniform branch
            const float* row = xr + hh * 64;
            #pragma unroll
            for (int u = 0; u < 6; ++u) {
                int wb4 = s * 4 - 1 + u;          // wave-uniform branch
                if ((unsigned)wb4 < 16u) {
                    float4 f = *(const float4*)(row + wb4 * 4);
                    int j = u * 4;
                    vs[j]     += f.x; vm[j]     = fmaxf(vm[j],     f.x);
                    vs[j + 1] += f.y; vm[j + 1] = fmaxf(vm[j + 1], f.y);
                    vs[j + 2] += f.z; vm[j + 2] = fmaxf(vm[j + 2], f.z);
                    vs[j + 3] += f.w; vm[j + 3] = fmaxf(vm[j + 3], f.w);
                }
            }
        }
    }
    // horizontal: OOB-w columns hold vs=0 (sum-correct) and vm=-inf (max-correct)
    size_t nb = ((size_t)b * 4096 + h * 64 + s * 16) * 512 + c;
    #pragma unroll
    for (int i = 0; i < 16; ++i) {
        float sum = vs[i + 3] + vs[i + 4] + vs[i + 5];
        float mx  = fmaxf(fmaxf(vm[i + 3], vm[i + 4]), vm[i + 5]);
        cat[nb + (size_t)i * 512]       = f2u(sum * (1.f / 9.f));
        cat[nb + (size_t)i * 512 + 256] = f2u(mx);
    }
}

// Kernel 2: MFMA projections. Block tile 128n x 64o, wave quadrant 64n x 32o.
// V output (blockIdx.y>=1) goes through an LDS transpose for coalesced stores.
__global__ __launch_bounds__(256) void proj_kernel(
    const ushort* __restrict__ cat,
    const float* __restrict__ wb, const float* __restrict__ bb,
    const float* __restrict__ wc, const float* __restrict__ bc,
    const float* __restrict__ wd, const float* __restrict__ bd,
    ushort* __restrict__ Qb, ushort* __restrict__ Kb, ushort* __restrict__ Vt) {
    __shared__ __align__(16) ushort As[128][72];
    __shared__ __align__(16) ushort Wsm[64][72];
    __shared__ __align__(16) ushort Vls[64][132];   // [o_local][n_local] transpose
    int tid = threadIdx.x;
    int l = tid & 63, w = tid >> 6;
    int lm = l & 15, q = l >> 4;
    int wn = w & 1, wo = w >> 1;
    int row0 = blockIdx.x * 128;
    int col0 = blockIdx.y * 64;
    f4v acc[4][2];
    #pragma unroll
    for (int mt = 0; mt < 4; ++mt)
        #pragma unroll
        for (int ot = 0; ot < 2; ++ot)
            #pragma unroll
            for (int i = 0; i < 4; ++i) acc[mt][ot][i] = 0.f;

    int wrow_o = col0 + (tid >> 2);
    const float* wr = (wrow_o < 32) ? wb + (size_t)wrow_o * 512
                    : (wrow_o < 64) ? wc + (size_t)(wrow_o - 32) * 512
                                    : wd + (size_t)(wrow_o - 64) * 512;
    const ushort* arow = cat + (size_t)(row0 + (tid >> 1)) * 512 + (tid & 1) * 32;

    for (int kc = 0; kc < 8; ++kc) {
        {   // stage A chunk [128][64] bf16
            int r = tid >> 1, ko = (tid & 1) * 32;
            const ushort* src = arow + kc * 64;
            #pragma unroll
            for (int u = 0; u < 4; ++u)
                *(uint4*)&As[r][ko + u * 8] = *(const uint4*)(src + u * 8);
        }
        {   // stage W chunk [64][64], fp32 -> bf16
            int r = tid >> 2, ko = (tid & 3) * 16;
            const float* s = wr + kc * 64 + ko;
            ushort tmp[16];
            #pragma unroll
            for (int u = 0; u < 16; ++u) tmp[u] = f2u(s[u]);
            *(uint4*)&Wsm[r][ko]     = *(uint4*)&tmp[0];
            *(uint4*)&Wsm[r][ko + 8] = *(uint4*)&tmp[8];
        }
        __syncthreads();
        #pragma unroll
        for (int ks = 0; ks < 2; ++ks) {
            int kk = ks * 32;
            s8v a[4], bfr[2];
            #pragma unroll
            for (int mt = 0; mt < 4; ++mt)
                a[mt] = *(const s8v*)&As[wn * 64 + mt * 16 + lm][kk + q * 8];
            #pragma unroll
            for (int ot = 0; ot < 2; ++ot)
                bfr[ot] = *(const s8v*)&Wsm[wo * 32 + ot * 16 + lm][kk + q * 8];
            #pragma unroll
            for (int mt = 0; mt < 4; ++mt)
                #pragma unroll
                for (int ot = 0; ot < 2; ++ot)
                    acc[mt][ot] = __builtin_amdgcn_mfma_f32_16x16x32_bf16(
                        a[mt], bfr[ot], acc[mt][ot], 0, 0, 0);
        }
        __syncthreads();
    }
    if (col0 == 0) {
        // Q/K epilogue: scalar stores (small outputs)
        #pragma unroll
        for (int ot = 0; ot < 2; ++ot) {
            int o = wo * 32 + ot * 16 + lm;
            float bias = (o < 32) ? bb[o] : bc[o - 32];
            #pragma unroll
            for (int mt = 0; mt < 4; ++mt) {
                int n = row0 + wn * 64 + mt * 16 + q * 4;
                if (o < 32) {
                    #pragma unroll
                    for (int r = 0; r < 4; ++r)
                        Qb[(size_t)(n + r) * 32 + o] = f2u(acc[mt][ot][r] + bias);
                } else {
                    #pragma unroll
                    for (int r = 0; r < 4; ++r)
                        Kb[(size_t)(n + r) * 32 + (o - 32)] = f2u(acc[mt][ot][r] + bias);
                }
            }
        }
    } else {
        // V epilogue: LDS transpose -> coalesced 64B-granule stores
        #pragma unroll
        for (int ot = 0; ot < 2; ++ot) {
            int ol = wo * 32 + ot * 16 + lm;
            float bias = bd[col0 - 64 + ol];
            #pragma unroll
            for (int mt = 0; mt < 4; ++mt) {
                int nl = wn * 64 + mt * 16 + q * 4;
                #pragma unroll
                for (int r = 0; r < 4; ++r)
                    Vls[ol][nl + r] = f2u(acc[mt][ot][r] + bias);
            }
        }
        __syncthreads();
        int orow = tid >> 2, nch = (tid & 3) * 32;
        int bidx = row0 >> 12, nn = row0 & 4095;
        int cch = col0 - 64 + orow;
        ushort* dst = Vt + ((size_t)(bidx * 256 + cch)) * 4096 + nn + nch;
        #pragma unroll
        for (int u = 0; u < 4; ++u)
            *(uint4*)(dst + u * 8) = *(const uint4*)&Vls[orow][nch + u * 8];
    }
}

// Kernel 3: MFMA flash attention + residual. 256 blocks (1/CU), 4 waves.
// Q/K frags loaded straight from global in MFMA layout (no LDS); V double-
// buffered through registers so every global load has a full phase of overlap.
__global__ __launch_bounds__(256) void attn_kernel(
    const ushort* __restrict__ Qb, const ushort* __restrict__ Kb,
    const ushort* __restrict__ Vt, const float* __restrict__ x,
    const float* __restrict__ alphap, float* __restrict__ out) {
    __shared__ __align__(16) ushort Ps[2][64][72];
    __shared__ __align__(16) ushort Vts[2][256][72];
    __shared__ float Lpart[4][64];
    __shared__ float Lrow[64];
    int tid = threadIdx.x;
    int l = tid & 63, w = tid >> 6;
    int lm = l & 15, q = l >> 4;
    int bid = blockIdx.x;
    int xcd = bid & 7;
    int b = xcd & 3;                                  // one batch per XCD pair
    int mblk = (bid >> 3) + ((xcd >> 2) << 5);
    int m0 = mblk << 6;
    size_t bN = (size_t)b << 12;

    const ushort* kb = Kb + bN * 32;
    const ushort* vb = Vt + ((size_t)b * 256) * 4096;
    int vcc = tid >> 3, vnq = (tid & 7) * 8;          // V staging mapping

    // Q fragments: direct global load in A layout (contiguous 16B per lane)
    s8v Qf[4];
    const ushort* qb = Qb + (bN + m0) * 32;
    #pragma unroll
    for (int mt = 0; mt < 4; ++mt)
        Qf[mt] = *(const s8v*)(qb + (size_t)(mt * 16 + lm) * 32 + q * 8);

    // prologue: K frag for tile 0, V regs for tile 0
    s8v kf = *(const s8v*)(kb + (size_t)(w * 16 + lm) * 32 + q * 8);
    uint4 vreg[8];
    #pragma unroll
    for (int pp = 0; pp < 8; ++pp)
        vreg[pp] = *(const uint4*)(vb + (size_t)(pp * 32 + vcc) * 4096 + vnq);

    f4v acc[4][4];
    #pragma unroll
    for (int mt = 0; mt < 4; ++mt)
        #pragma unroll
        for (int ct = 0; ct < 4; ++ct)
            #pragma unroll
            for (int i = 0; i < 4; ++i) acc[mt][ct][i] = 0.f;
    float Lacc[4][4] = {{0.f,0.f,0.f,0.f},{0.f,0.f,0.f,0.f},
                        {0.f,0.f,0.f,0.f},{0.f,0.f,0.f,0.f}};

    for (int t = 0; t < 64; ++t) {
        int p = t & 1;
        int n1 = (t + 1) << 6;
        // prefetch next K frag (drains at the barrier below; ~full phase overlap)
        s8v kfn = kf;
        if (t < 63)
            kfn = *(const s8v*)(kb + (size_t)(n1 + w * 16 + lm) * 32 + q * 8);
        // scores (registers only): S[m][n-strip w], then exp
        float pe[4][4];
        #pragma unroll
        for (int mt = 0; mt < 4; ++mt) {
            f4v S;
            #pragma unroll
            for (int i = 0; i < 4; ++i) S[i] = 0.f;
            S = __builtin_amdgcn_mfma_f32_16x16x32_bf16(Qf[mt], kf, S, 0, 0, 0);
            #pragma unroll
            for (int r = 0; r < 4; ++r) {
                float e = __expf(fminf(S[r], 60.f));
                pe[mt][r] = e;
                Lacc[mt][r] += e;
            }
        }
        __syncthreads();   // prev PV done; V(t)/K(t+1) loads drained
        // commit V(t) regs -> LDS, write P(t)
        #pragma unroll
        for (int pp = 0; pp < 8; ++pp)
            *(uint4*)&Vts[p][pp * 32 + vcc][vnq] = vreg[pp];
        #pragma unroll
        for (int mt = 0; mt < 4; ++mt)
            #pragma unroll
            for (int r = 0; r < 4; ++r)
                Ps[p][mt * 16 + q * 4 + r][w * 16 + lm] = f2u(pe[mt][r]);
        __syncthreads();   // staging visible
        // issue V(t+1) loads: in flight across the whole PV + next scores phase
        if (t < 63) {
            #pragma unroll
            for (int pp = 0; pp < 8; ++pp)
                vreg[pp] = *(const uint4*)(vb + (size_t)(pp * 32 + vcc) * 4096
                                           + n1 + vnq);
        }
        // PV: O[m][c-strip w] += P * V
        s8v Af[4][2];
        #pragma unroll
        for (int mt = 0; mt < 4; ++mt) {
            Af[mt][0] = *(const s8v*)&Ps[p][mt * 16 + lm][q * 8];
            Af[mt][1] = *(const s8v*)&Ps[p][mt * 16 + lm][32 + q * 8];
        }
        #pragma unroll
        for (int ct = 0; ct < 4; ++ct) {
            int cc = w * 64 + ct * 16 + lm;
            s8v B0 = *(const s8v*)&Vts[p][cc][q * 8];
            s8v B1 = *(const s8v*)&Vts[p][cc][32 + q * 8];
            #pragma unroll
            for (int mt = 0; mt < 4; ++mt) {
                acc[mt][ct] = __builtin_amdgcn_mfma_f32_16x16x32_bf16(
                    Af[mt][0], B0, acc[mt][ct], 0, 0, 0);
                acc[mt][ct] = __builtin_amdgcn_mfma_f32_16x16x32_bf16(
                    Af[mt][1], B1, acc[mt][ct], 0, 0, 0);
            }
        }
        kf = kfn;
    }
    // row sums: butterfly over the 16 strip-columns, then cross-wave add
    #pragma unroll
    for (int mt = 0; mt < 4; ++mt)
        #pragma unroll
        for (int r = 0; r < 4; ++r) {
            float v = Lacc[mt][r];
            v += __shfl_xor(v, 1, 64);
            v += __shfl_xor(v, 2, 64);
            v += __shfl_xor(v, 4, 64);
            v += __shfl_xor(v, 8, 64);
            Lacc[mt][r] = v;
        }
    if (lm == 0) {
        #pragma unroll
        for (int mt = 0; mt < 4; ++mt)
            #pragma unroll
            for (int r = 0; r < 4; ++r)
                Lpart[w][mt * 16 + q * 4 + r] = Lacc[mt][r];
    }
    __syncthreads();
    if (tid < 64)
        Lrow[tid] = Lpart[0][tid] + Lpart[1][tid] + Lpart[2][tid] + Lpart[3][tid];
    __syncthreads();
    // epilogue: out = alpha*(acc/L) + (1-alpha)*x
    float alpha = alphap[0];
    float ra = 1.f - alpha;
    #pragma unroll
    for (int mt = 0; mt < 4; ++mt) {
        float L0 = Lrow[mt * 16 + q * 4 + 0];
        float L1 = Lrow[mt * 16 + q * 4 + 1];
        float L2 = Lrow[mt * 16 + q * 4 + 2];
        float L3 = Lrow[mt * 16 + q * 4 + 3];
        #pragma unroll
        for (int ct = 0; ct < 4; ++ct) {
            int cc = w * 64 + ct * 16 + lm;
            size_t base = ((size_t)(b * 256 + cc)) * 4096 + m0 + mt * 16 + q * 4;
            float4 xv = *(const float4*)(x + base);
            float4 ov;
            ov.x = alpha * (acc[mt][ct][0] / L0) + ra * xv.x;
            ov.y = alpha * (acc[mt][ct][1] / L1) + ra * xv.y;
            ov.z = alpha * (acc[mt][ct][2] / L2) + ra * xv.z;
            ov.w = alpha * (acc[mt][ct][3] / L3) + ra * xv.w;
            *(float4*)(out + base) = ov;
        }
    }
}

extern "C" void kernel_launch(void* const* d_in, const int* in_sizes, int n_in,
                              void* d_out, int out_size, void* d_ws, size_t ws_size,
                              hipStream_t stream) {
    const float* x  = (const float*)d_in[0];
    const float* wb = (const float*)d_in[1];
    const float* bb = (const float*)d_in[2];
    const float* wc = (const float*)d_in[3];
    const float* bc = (const float*)d_in[4];
    const float* wd = (const float*)d_in[5];
    const float* bd = (const float*)d_in[6];
    const float* al = (const float*)d_in[7];
    float* out = (float*)d_out;

    char* ws = (char*)d_ws;
    ushort* cat = (ushort*)ws;                    // 16 MiB
    ushort* Qb  = (ushort*)(ws + 16777216);       //  1 MiB
    ushort* Kb  = (ushort*)(ws + 17825792);       //  1 MiB
    ushort* Vt  = (ushort*)(ws + 18874368);       //  8 MiB

    pool_kernel<<<dim3(1024), dim3(256), 0, stream>>>(x, cat);
    proj_kernel<<<dim3(128, 5), dim3(256), 0, stream>>>(cat, wb, bb, wc, bc, wd, bd,
                                                        Qb, Kb, Vt);
    attn_kernel<<<dim3(256), dim3(256), 0, stream>>>(Qb, Kb, Vt, x, al, out);
}

// Round 5
// 244.243 us; speedup vs baseline: 1.1886x; 1.1886x over previous
//
#include <hip/hip_runtime.h>
#include <hip/hip_bf16.h>

typedef __hip_bfloat16 bf16;
typedef __attribute__((ext_vector_type(8))) short s8v;   // 8 bf16 = 4 VGPR (MFMA A/B frag)
typedef __attribute__((ext_vector_type(4))) float f4v;   // MFMA C/D frag

__device__ __forceinline__ ushort f2u(float f) {
    bf16 h = __float2bfloat16(f);
    return *(ushort*)&h;
}

// ---------------------------------------------------------------------------
// B=4, C=256, H=W=64, N=4096. All inputs/outputs fp32; internal bf16.
// ws: cat  bf16 [16384][512]   @ 0          (16 MiB)
//     Qb   bf16 [16384][32]    @ 16777216   ( 1 MiB)
//     Kb   bf16 [16384][32]    @ 17825792   ( 1 MiB)
//     Vt   bf16 [4][256][4096] @ 18874368   ( 8 MiB)
// MFMA 16x16x32 bf16 layouts (m89/m120-verified):
//   A: lane holds A[m=lane&15][k=(lane>>4)*8+j]
//   B: lane holds B[k=(lane>>4)*8+j][n=lane&15]
//   C/D: lane holds D[row=(lane>>4)*4+r][col=lane&15]
// ---------------------------------------------------------------------------

// Kernel 1: 3x3 avg(/9, include-pad) + 3x3 max.
// Block = (b, h, cgroup of 64). Staging lanes=w (coalesced global), LDS
// transpose [dh][w][c] (compute reads 2-way free), stores lanes=c (coalesced).
__global__ __launch_bounds__(256) void pool_kernel(const float* __restrict__ x,
                                                   ushort* __restrict__ cat) {
    __shared__ float Xs[3][64][66];   // [dh][w][c'], pad 66: reads 2-way free
    int tid = threadIdx.x;
    int bid = blockIdx.x;
    int b = bid >> 8, h = (bid >> 2) & 63, cg = bid & 3;
    bool hasU = (h > 0), hasD = (h < 63);
    // stage: 12 passes x 256 thr, each a float4 (lanes = w4 -> coalesced)
    #pragma unroll
    for (int pp = 0; pp < 12; ++pp) {
        int linear = pp * 256 + tid;
        int w4 = linear & 15;
        int cs = (linear >> 4) & 63;
        int dh = linear >> 10;
        int hh = h + dh - 1;
        float4 f = {0.f, 0.f, 0.f, 0.f};
        if ((unsigned)hh < 64u)
            f = *(const float4*)(x + ((size_t)(b * 256 + cg * 64 + cs)) * 4096
                                 + hh * 64 + w4 * 4);
        Xs[dh][w4 * 4 + 0][cs] = f.x;
        Xs[dh][w4 * 4 + 1][cs] = f.y;
        Xs[dh][w4 * 4 + 2][cs] = f.z;
        Xs[dh][w4 * 4 + 3][cs] = f.w;
    }
    __syncthreads();
    int cs = tid & 63, ws = tid >> 6;        // thread: channel cs, 16-w strip ws
    float vs[18], vm[18];
    #pragma unroll
    for (int j = 0; j < 18; ++j) {
        int w = ws * 16 - 1 + j;
        if ((unsigned)w < 64u) {
            float u = Xs[0][w][cs], m = Xs[1][w][cs], d = Xs[2][w][cs];
            vs[j] = u + m + d;               // OOB rows staged 0: sum correct
            float mx = m;
            if (hasU) mx = fmaxf(mx, u);
            if (hasD) mx = fmaxf(mx, d);
            vm[j] = mx;
        } else { vs[j] = 0.f; vm[j] = -3.4e38f; }
    }
    size_t nb = ((size_t)b * 4096 + h * 64 + ws * 16) * 512 + cg * 64 + cs;
    #pragma unroll
    for (int i = 0; i < 16; ++i) {
        float sum = vs[i] + vs[i + 1] + vs[i + 2];
        float mx  = fmaxf(fmaxf(vm[i], vm[i + 1]), vm[i + 2]);
        cat[nb + (size_t)i * 512]       = f2u(sum * (1.f / 9.f));
        cat[nb + (size_t)i * 512 + 256] = f2u(mx);
    }
}

// Kernel 2: MFMA projections. Block tile 128n x 64o, wave quadrant 64n x 32o.
// V output (blockIdx.y>=1) goes through an LDS transpose for coalesced stores.
__global__ __launch_bounds__(256) void proj_kernel(
    const ushort* __restrict__ cat,
    const float* __restrict__ wb, const float* __restrict__ bb,
    const float* __restrict__ wc, const float* __restrict__ bc,
    const float* __restrict__ wd, const float* __restrict__ bd,
    ushort* __restrict__ Qb, ushort* __restrict__ Kb, ushort* __restrict__ Vt) {
    __shared__ __align__(16) ushort As[128][72];
    __shared__ __align__(16) ushort Wsm[64][72];
    __shared__ __align__(16) ushort Vls[64][132];   // [o_local][n_local] transpose
    int tid = threadIdx.x;
    int l = tid & 63, w = tid >> 6;
    int lm = l & 15, q = l >> 4;
    int wn = w & 1, wo = w >> 1;
    int row0 = blockIdx.x * 128;
    int col0 = blockIdx.y * 64;
    f4v acc[4][2];
    #pragma unroll
    for (int mt = 0; mt < 4; ++mt)
        #pragma unroll
        for (int ot = 0; ot < 2; ++ot)
            #pragma unroll
            for (int i = 0; i < 4; ++i) acc[mt][ot][i] = 0.f;

    int wrow_o = col0 + (tid >> 2);
    const float* wr = (wrow_o < 32) ? wb + (size_t)wrow_o * 512
                    : (wrow_o < 64) ? wc + (size_t)(wrow_o - 32) * 512
                                    : wd + (size_t)(wrow_o - 64) * 512;
    const ushort* arow = cat + (size_t)(row0 + (tid >> 1)) * 512 + (tid & 1) * 32;

    for (int kc = 0; kc < 8; ++kc) {
        {   // stage A chunk [128][64] bf16
            int r = tid >> 1, ko = (tid & 1) * 32;
            const ushort* src = arow + kc * 64;
            #pragma unroll
            for (int u = 0; u < 4; ++u)
                *(uint4*)&As[r][ko + u * 8] = *(const uint4*)(src + u * 8);
        }
        {   // stage W chunk [64][64], fp32 -> bf16
            int r = tid >> 2, ko = (tid & 3) * 16;
            const float* s = wr + kc * 64 + ko;
            ushort tmp[16];
            #pragma unroll
            for (int u = 0; u < 16; ++u) tmp[u] = f2u(s[u]);
            *(uint4*)&Wsm[r][ko]     = *(uint4*)&tmp[0];
            *(uint4*)&Wsm[r][ko + 8] = *(uint4*)&tmp[8];
        }
        __syncthreads();
        #pragma unroll
        for (int ks = 0; ks < 2; ++ks) {
            int kk = ks * 32;
            s8v a[4], bfr[2];
            #pragma unroll
            for (int mt = 0; mt < 4; ++mt)
                a[mt] = *(const s8v*)&As[wn * 64 + mt * 16 + lm][kk + q * 8];
            #pragma unroll
            for (int ot = 0; ot < 2; ++ot)
                bfr[ot] = *(const s8v*)&Wsm[wo * 32 + ot * 16 + lm][kk + q * 8];
            #pragma unroll
            for (int mt = 0; mt < 4; ++mt)
                #pragma unroll
                for (int ot = 0; ot < 2; ++ot)
                    acc[mt][ot] = __builtin_amdgcn_mfma_f32_16x16x32_bf16(
                        a[mt], bfr[ot], acc[mt][ot], 0, 0, 0);
        }
        __syncthreads();
    }
    if (col0 == 0) {
        // Q/K epilogue: scalar stores (small outputs)
        #pragma unroll
        for (int ot = 0; ot < 2; ++ot) {
            int o = wo * 32 + ot * 16 + lm;
            float bias = (o < 32) ? bb[o] : bc[o - 32];
            #pragma unroll
            for (int mt = 0; mt < 4; ++mt) {
                int n = row0 + wn * 64 + mt * 16 + q * 4;
                if (o < 32) {
                    #pragma unroll
                    for (int r = 0; r < 4; ++r)
                        Qb[(size_t)(n + r) * 32 + o] = f2u(acc[mt][ot][r] + bias);
                } else {
                    #pragma unroll
                    for (int r = 0; r < 4; ++r)
                        Kb[(size_t)(n + r) * 32 + (o - 32)] = f2u(acc[mt][ot][r] + bias);
                }
            }
        }
    } else {
        // V epilogue: LDS transpose -> coalesced 64B-granule stores
        #pragma unroll
        for (int ot = 0; ot < 2; ++ot) {
            int ol = wo * 32 + ot * 16 + lm;
            float bias = bd[col0 - 64 + ol];
            #pragma unroll
            for (int mt = 0; mt < 4; ++mt) {
                int nl = wn * 64 + mt * 16 + q * 4;
                #pragma unroll
                for (int r = 0; r < 4; ++r)
                    Vls[ol][nl + r] = f2u(acc[mt][ot][r] + bias);
            }
        }
        __syncthreads();
        int orow = tid >> 2, nch = (tid & 3) * 32;
        int bidx = row0 >> 12, nn = row0 & 4095;
        int cch = col0 - 64 + orow;
        ushort* dst = Vt + ((size_t)(bidx * 256 + cch)) * 4096 + nn + nch;
        #pragma unroll
        for (int u = 0; u < 4; ++u)
            *(uint4*)(dst + u * 8) = *(const uint4*)&Vls[orow][nch + u * 8];
    }
}

// Kernel 3: MFMA flash attention + residual. 256 blocks (1/CU), 4 waves.
// Q/K/V fragments ALL loaded straight from global in MFMA layout (V stays in
// the XCD-local L2: 2MB/batch). LDS holds only the P round-trip (double-
// buffered -> ONE barrier per tile). K/V frags for t+1 prefetched under the
// PV MFMA burst.
__global__ __launch_bounds__(256, 1) void attn_kernel(
    const ushort* __restrict__ Qb, const ushort* __restrict__ Kb,
    const ushort* __restrict__ Vt, const float* __restrict__ x,
    const float* __restrict__ alphap, float* __restrict__ out) {
    __shared__ __align__(16) ushort Ps[2][64][72];  // P write free; Af read 2-way
    __shared__ float Lpart[4][64];
    __shared__ float Lrow[64];
    int tid = threadIdx.x;
    int l = tid & 63, w = tid >> 6;
    int lm = l & 15, q = l >> 4;
    int bid = blockIdx.x;
    int xcd = bid & 7;
    int b = xcd & 3;                                  // batch pinned per XCD pair
    int mblk = (bid >> 3) + ((xcd >> 2) << 5);
    int m0 = mblk << 6;
    size_t bN = (size_t)b << 12;

    const ushort* kb = Kb + bN * 32 + (size_t)(w * 16 + lm) * 32 + q * 8;
    // V B-frag row pointers: lane (lm,q) of wave w reads Vt row w*64+ct*16+lm
    const ushort* vrow[4];
    #pragma unroll
    for (int ct = 0; ct < 4; ++ct)
        vrow[ct] = Vt + ((size_t)b * 256 + w * 64 + ct * 16 + lm) * 4096 + q * 8;

    // Q fragments: direct global load in A layout (contiguous 16B per lane)
    s8v Qf[4];
    const ushort* qb = Qb + (bN + m0) * 32;
    #pragma unroll
    for (int mt = 0; mt < 4; ++mt)
        Qf[mt] = *(const s8v*)(qb + (size_t)(mt * 16 + lm) * 32 + q * 8);

    // prologue: K frag + V frags for tile 0
    s8v kf = *(const s8v*)(kb);
    s8v vf[8];
    #pragma unroll
    for (int ct = 0; ct < 4; ++ct) {
        vf[ct * 2 + 0] = *(const s8v*)(vrow[ct]);
        vf[ct * 2 + 1] = *(const s8v*)(vrow[ct] + 32);
    }

    f4v acc[4][4];
    #pragma unroll
    for (int mt = 0; mt < 4; ++mt)
        #pragma unroll
        for (int ct = 0; ct < 4; ++ct)
            #pragma unroll
            for (int i = 0; i < 4; ++i) acc[mt][ct][i] = 0.f;
    float Lacc[4][4] = {{0.f,0.f,0.f,0.f},{0.f,0.f,0.f,0.f},
                        {0.f,0.f,0.f,0.f},{0.f,0.f,0.f,0.f}};

    for (int t = 0; t < 64; ++t) {
        int p = t & 1;
        // scores: 4 independent MFMAs (all register operands)
        f4v S[4];
        #pragma unroll
        for (int mt = 0; mt < 4; ++mt) {
            #pragma unroll
            for (int i = 0; i < 4; ++i) S[mt][i] = 0.f;
            S[mt] = __builtin_amdgcn_mfma_f32_16x16x32_bf16(Qf[mt], kf, S[mt], 0, 0, 0);
        }
        // exp + P write (layout: row = m, col = n-strip; both LDS-conflict-free)
        #pragma unroll
        for (int mt = 0; mt < 4; ++mt)
            #pragma unroll
            for (int r = 0; r < 4; ++r) {
                float e = __expf(fminf(S[mt][r], 60.f));
                Lacc[mt][r] += e;
                Ps[p][mt * 16 + q * 4 + r][w * 16 + lm] = f2u(e);
            }
        __syncthreads();   // P(t) visible; prior Af reads of this buffer drained
        // prefetch K(t+1), V(t+1) frags: covered by Af reads + 32 PV MFMAs
        s8v kfn = kf, vfn[8];
        #pragma unroll
        for (int i = 0; i < 8; ++i) vfn[i] = vf[i];
        if (t < 63) {
            int n1 = (t + 1) << 6;
            kfn = *(const s8v*)(kb + (size_t)n1 * 32);
            #pragma unroll
            for (int ct = 0; ct < 4; ++ct) {
                vfn[ct * 2 + 0] = *(const s8v*)(vrow[ct] + n1);
                vfn[ct * 2 + 1] = *(const s8v*)(vrow[ct] + n1 + 32);
            }
        }
        // A-frags of P from LDS (2-way max = free)
        s8v Af[4][2];
        #pragma unroll
        for (int mt = 0; mt < 4; ++mt) {
            Af[mt][0] = *(const s8v*)&Ps[p][mt * 16 + lm][q * 8];
            Af[mt][1] = *(const s8v*)&Ps[p][mt * 16 + lm][32 + q * 8];
        }
        // PV: kh outer -> 16 independent accumulators between reuses
        #pragma unroll
        for (int kh = 0; kh < 2; ++kh)
            #pragma unroll
            for (int ct = 0; ct < 4; ++ct)
                #pragma unroll
                for (int mt = 0; mt < 4; ++mt)
                    acc[mt][ct] = __builtin_amdgcn_mfma_f32_16x16x32_bf16(
                        Af[mt][kh], vf[ct * 2 + kh], acc[mt][ct], 0, 0, 0);
        kf = kfn;
        #pragma unroll
        for (int i = 0; i < 8; ++i) vf[i] = vfn[i];
    }
    // row sums: butterfly over the 16 strip-columns, then cross-wave add
    #pragma unroll
    for (int mt = 0; mt < 4; ++mt)
        #pragma unroll
        for (int r = 0; r < 4; ++r) {
            float v = Lacc[mt][r];
            v += __shfl_xor(v, 1, 64);
            v += __shfl_xor(v, 2, 64);
            v += __shfl_xor(v, 4, 64);
            v += __shfl_xor(v, 8, 64);
            Lacc[mt][r] = v;
        }
    if (lm == 0) {
        #pragma unroll
        for (int mt = 0; mt < 4; ++mt)
            #pragma unroll
            for (int r = 0; r < 4; ++r)
                Lpart[w][mt * 16 + q * 4 + r] = Lacc[mt][r];
    }
    __syncthreads();
    if (tid < 64)
        Lrow[tid] = Lpart[0][tid] + Lpart[1][tid] + Lpart[2][tid] + Lpart[3][tid];
    __syncthreads();
    // epilogue: out = alpha*(acc/L) + (1-alpha)*x
    float alpha = alphap[0];
    float ra = 1.f - alpha;
    #pragma unroll
    for (int mt = 0; mt < 4; ++mt) {
        float L0 = Lrow[mt * 16 + q * 4 + 0];
        float L1 = Lrow[mt * 16 + q * 4 + 1];
        float L2 = Lrow[mt * 16 + q * 4 + 2];
        float L3 = Lrow[mt * 16 + q * 4 + 3];
        #pragma unroll
        for (int ct = 0; ct < 4; ++ct) {
            int cc = w * 64 + ct * 16 + lm;
            size_t base = ((size_t)(b * 256 + cc)) * 4096 + m0 + mt * 16 + q * 4;
            float4 xv = *(const float4*)(x + base);
            float4 ov;
            ov.x = alpha * (acc[mt][ct][0] / L0) + ra * xv.x;
            ov.y = alpha * (acc[mt][ct][1] / L1) + ra * xv.y;
            ov.z = alpha * (acc[mt][ct][2] / L2) + ra * xv.z;
            ov.w = alpha * (acc[mt][ct][3] / L3) + ra * xv.w;
            *(float4*)(out + base) = ov;
        }
    }
}

extern "C" void kernel_launch(void* const* d_in, const int* in_sizes, int n_in,
                              void* d_out, int out_size, void* d_ws, size_t ws_size,
                              hipStream_t stream) {
    const float* x  = (const float*)d_in[0];
    const float* wb = (const float*)d_in[1];
    const float* bb = (const float*)d_in[2];
    const float* wc = (const float*)d_in[3];
    const float* bc = (const float*)d_in[4];
    const float* wd = (const float*)d_in[5];
    const float* bd = (const float*)d_in[6];
    const float* al = (const float*)d_in[7];
    float* out = (float*)d_out;

    char* ws = (char*)d_ws;
    ushort* cat = (ushort*)ws;                    // 16 MiB
    ushort* Qb  = (ushort*)(ws + 16777216);       //  1 MiB
    ushort* Kb  = (ushort*)(ws + 17825792);       //  1 MiB
    ushort* Vt  = (ushort*)(ws + 18874368);       //  8 MiB

    pool_kernel<<<dim3(1024), dim3(256), 0, stream>>>(x, cat);
    proj_kernel<<<dim3(128, 5), dim3(256), 0, stream>>>(cat, wb, bb, wc, bc, wd, bd,
                                                        Qb, Kb, Vt);
    attn_kernel<<<dim3(256), dim3(256), 0, stream>>>(Qb, Kb, Vt, x, al, out);
}

// Round 6
// 169.129 us; speedup vs baseline: 1.7165x; 1.4441x over previous
//
#include <hip/hip_runtime.h>
#include <hip/hip_bf16.h>

typedef __hip_bfloat16 bf16;
typedef __attribute__((ext_vector_type(8))) short s8v;   // 8 bf16 = 4 VGPR (MFMA A/B frag)
typedef __attribute__((ext_vector_type(4))) float f4v;   // MFMA C/D frag

__device__ __forceinline__ ushort f2u(float f) {
    bf16 h = __float2bfloat16(f);
    return *(ushort*)&h;
}

// ---------------------------------------------------------------------------
// B=4, C=256, H=W=64, N=4096. All inputs/outputs fp32; internal bf16.
// ws: cat  bf16 [16384][512]   @ 0          (16 MiB)
//     Qb   bf16 [16384][32]    @ 16777216   ( 1 MiB)
//     Kb   bf16 [16384][32]    @ 17825792   ( 1 MiB)
//     Vf   bf16 frag-ordered   @ 18874368   ( 8 MiB)
// Vf layout: element (b, c, n) at
//   b*1048576 + (n>>5)*8192 + (c>>4)*512 + (((n>>3)&3)*16 + (c&15))*8 + (n&7)
// so an MFMA B-frag load is one contiguous 1KB per wave (lane l reads l*8..+8).
// MFMA 16x16x32 bf16 layouts (m89/m120-verified):
//   A: lane holds A[m=lane&15][k=(lane>>4)*8+j]
//   B: lane holds B[k=(lane>>4)*8+j][n=lane&15]
//   C/D: lane holds D[row=(lane>>4)*4+r][col=lane&15]
// ---------------------------------------------------------------------------

// Kernel 1: 3x3 avg(/9, include-pad) + 3x3 max.
__global__ __launch_bounds__(256) void pool_kernel(const float* __restrict__ x,
                                                   ushort* __restrict__ cat) {
    __shared__ float Xs[3][64][66];   // [dh][w][c'], pad 66
    int tid = threadIdx.x;
    int bid = blockIdx.x;
    int b = bid >> 8, h = (bid >> 2) & 63, cg = bid & 3;
    bool hasU = (h > 0), hasD = (h < 63);
    #pragma unroll
    for (int pp = 0; pp < 12; ++pp) {
        int linear = pp * 256 + tid;
        int w4 = linear & 15;
        int cs = (linear >> 4) & 63;
        int dh = linear >> 10;
        int hh = h + dh - 1;
        float4 f = {0.f, 0.f, 0.f, 0.f};
        if ((unsigned)hh < 64u)
            f = *(const float4*)(x + ((size_t)(b * 256 + cg * 64 + cs)) * 4096
                                 + hh * 64 + w4 * 4);
        Xs[dh][w4 * 4 + 0][cs] = f.x;
        Xs[dh][w4 * 4 + 1][cs] = f.y;
        Xs[dh][w4 * 4 + 2][cs] = f.z;
        Xs[dh][w4 * 4 + 3][cs] = f.w;
    }
    __syncthreads();
    int cs = tid & 63, ws = tid >> 6;
    float vs[18], vm[18];
    #pragma unroll
    for (int j = 0; j < 18; ++j) {
        int w = ws * 16 - 1 + j;
        if ((unsigned)w < 64u) {
            float u = Xs[0][w][cs], m = Xs[1][w][cs], d = Xs[2][w][cs];
            vs[j] = u + m + d;
            float mx = m;
            if (hasU) mx = fmaxf(mx, u);
            if (hasD) mx = fmaxf(mx, d);
            vm[j] = mx;
        } else { vs[j] = 0.f; vm[j] = -3.4e38f; }
    }
    size_t nb = ((size_t)b * 4096 + h * 64 + ws * 16) * 512 + cg * 64 + cs;
    #pragma unroll
    for (int i = 0; i < 16; ++i) {
        float sum = vs[i] + vs[i + 1] + vs[i + 2];
        float mx  = fmaxf(fmaxf(vm[i], vm[i + 1]), vm[i + 2]);
        cat[nb + (size_t)i * 512]       = f2u(sum * (1.f / 9.f));
        cat[nb + (size_t)i * 512 + 256] = f2u(mx);
    }
}

// Kernel 2: MFMA projections. Block tile 128n x 64o, wave quadrant 64n x 32o.
// V epilogue writes the frag-ordered Vf layout via the LDS transpose.
__global__ __launch_bounds__(256) void proj_kernel(
    const ushort* __restrict__ cat,
    const float* __restrict__ wb, const float* __restrict__ bb,
    const float* __restrict__ wc, const float* __restrict__ bc,
    const float* __restrict__ wd, const float* __restrict__ bd,
    ushort* __restrict__ Qb, ushort* __restrict__ Kb, ushort* __restrict__ Vf) {
    __shared__ __align__(16) ushort As[128][72];
    __shared__ __align__(16) ushort Wsm[64][72];
    __shared__ __align__(16) ushort Vls[64][136];   // [o_local][n_local], 16B rows
    int tid = threadIdx.x;
    int l = tid & 63, w = tid >> 6;
    int lm = l & 15, q = l >> 4;
    int wn = w & 1, wo = w >> 1;
    int row0 = blockIdx.x * 128;     // n-base
    int col0 = blockIdx.y * 64;      // o-base
    f4v acc[4][2];
    #pragma unroll
    for (int mt = 0; mt < 4; ++mt)
        #pragma unroll
        for (int ot = 0; ot < 2; ++ot)
            #pragma unroll
            for (int i = 0; i < 4; ++i) acc[mt][ot][i] = 0.f;

    int wrow_o = col0 + (tid >> 2);
    const float* wr = (wrow_o < 32) ? wb + (size_t)wrow_o * 512
                    : (wrow_o < 64) ? wc + (size_t)(wrow_o - 32) * 512
                                    : wd + (size_t)(wrow_o - 64) * 512;
    const ushort* arow = cat + (size_t)(row0 + (tid >> 1)) * 512 + (tid & 1) * 32;

    for (int kc = 0; kc < 8; ++kc) {
        {
            int r = tid >> 1, ko = (tid & 1) * 32;
            const ushort* src = arow + kc * 64;
            #pragma unroll
            for (int u = 0; u < 4; ++u)
                *(uint4*)&As[r][ko + u * 8] = *(const uint4*)(src + u * 8);
        }
        {
            int r = tid >> 2, ko = (tid & 3) * 16;
            const float* s = wr + kc * 64 + ko;
            ushort tmp[16];
            #pragma unroll
            for (int u = 0; u < 16; ++u) tmp[u] = f2u(s[u]);
            *(uint4*)&Wsm[r][ko]     = *(uint4*)&tmp[0];
            *(uint4*)&Wsm[r][ko + 8] = *(uint4*)&tmp[8];
        }
        __syncthreads();
        #pragma unroll
        for (int ks = 0; ks < 2; ++ks) {
            int kk = ks * 32;
            s8v a[4], bfr[2];
            #pragma unroll
            for (int mt = 0; mt < 4; ++mt)
                a[mt] = *(const s8v*)&As[wn * 64 + mt * 16 + lm][kk + q * 8];
            #pragma unroll
            for (int ot = 0; ot < 2; ++ot)
                bfr[ot] = *(const s8v*)&Wsm[wo * 32 + ot * 16 + lm][kk + q * 8];
            #pragma unroll
            for (int mt = 0; mt < 4; ++mt)
                #pragma unroll
                for (int ot = 0; ot < 2; ++ot)
                    acc[mt][ot] = __builtin_amdgcn_mfma_f32_16x16x32_bf16(
                        a[mt], bfr[ot], acc[mt][ot], 0, 0, 0);
        }
        __syncthreads();
    }
    if (col0 == 0) {
        #pragma unroll
        for (int ot = 0; ot < 2; ++ot) {
            int o = wo * 32 + ot * 16 + lm;
            float bias = (o < 32) ? bb[o] : bc[o - 32];
            #pragma unroll
            for (int mt = 0; mt < 4; ++mt) {
                int n = row0 + wn * 64 + mt * 16 + q * 4;
                if (o < 32) {
                    #pragma unroll
                    for (int r = 0; r < 4; ++r)
                        Qb[(size_t)(n + r) * 32 + o] = f2u(acc[mt][ot][r] + bias);
                } else {
                    #pragma unroll
                    for (int r = 0; r < 4; ++r)
                        Kb[(size_t)(n + r) * 32 + (o - 32)] = f2u(acc[mt][ot][r] + bias);
                }
            }
        }
    } else {
        // V epilogue: LDS transpose -> frag-ordered Vf stores (256B contiguous)
        #pragma unroll
        for (int ot = 0; ot < 2; ++ot) {
            int ol = wo * 32 + ot * 16 + lm;
            float bias = bd[col0 - 64 + ol];
            #pragma unroll
            for (int mt = 0; mt < 4; ++mt) {
                int nl = wn * 64 + mt * 16 + q * 4;
                #pragma unroll
                for (int r = 0; r < 4; ++r)
                    Vls[ol][nl + r] = f2u(acc[mt][ot][r] + bias);
            }
        }
        __syncthreads();
        int ol = tid >> 2;               // c-local 0..63
        int nch = (tid & 3) * 32;        // n-local chunk (32-aligned)
        int c = col0 - 64 + ol;
        int lmv = c & 15, cb = c >> 4;
        int bidx = row0 >> 12;
        int nglob = (row0 & 4095) + nch;
        size_t fbase = ((size_t)bidx << 20) + (size_t)(nglob >> 5) * 8192
                       + (size_t)cb * 512;
        #pragma unroll
        for (int qv = 0; qv < 4; ++qv)
            *(uint4*)(Vf + fbase + (qv * 16 + lmv) * 8)
                = *(const uint4*)&Vls[ol][nch + qv * 8];
    }
}

// Kernel 3: MFMA flash attention + residual.
// 512 blocks (2/CU -> 2 waves/SIMD TLP), M=32 per block, 4 waves.
// Q/K/V frags all direct global loads (V via frag-ordered Vf: 1KB coalesced
// per frag). LDS = P round-trip only, double-buffered, ONE barrier per tile.
// 2x-unrolled K/V register ping-pong (no copy movs).
__global__ __launch_bounds__(256, 2) void attn_kernel(
    const ushort* __restrict__ Qb, const ushort* __restrict__ Kb,
    const ushort* __restrict__ Vf, const float* __restrict__ x,
    const float* __restrict__ alphap, float* __restrict__ out) {
    __shared__ __align__(16) ushort Ps[2][32][72];
    __shared__ float Lpart[4][32];
    __shared__ float Lrow[32];
    int tid = threadIdx.x;
    int l = tid & 63, w = tid >> 6;
    int lm = l & 15, q = l >> 4;
    int bid = blockIdx.x;
    int xcd = bid & 7;
    int b = xcd & 3;                                 // batch pinned per XCD pair
    int mblk = (bid >> 3) + ((xcd >> 2) << 6);       // 0..127
    int m0 = mblk << 5;
    size_t bN = (size_t)b << 12;

    const ushort* kb  = Kb + (bN + w * 16 + lm) * 32 + q * 8;
    const ushort* vfb = Vf + ((size_t)b << 20) + (size_t)(w * 4) * 512
                        + (size_t)l * 8;

    s8v Qf[2];
    const ushort* qb = Qb + (bN + m0) * 32;
    #pragma unroll
    for (int mt = 0; mt < 2; ++mt)
        Qf[mt] = *(const s8v*)(qb + (size_t)(mt * 16 + lm) * 32 + q * 8);

    f4v acc0[4], acc1[4];
    #pragma unroll
    for (int ct = 0; ct < 4; ++ct)
        #pragma unroll
        for (int i = 0; i < 4; ++i) { acc0[ct][i] = 0.f; acc1[ct][i] = 0.f; }
    float Lacc0[4] = {0.f, 0.f, 0.f, 0.f};
    float Lacc1[4] = {0.f, 0.f, 0.f, 0.f};

    // prologue: tile 0 into register set A
    s8v kfA, kfB, vfA[8], vfB[8];
    kfA = *(const s8v*)kb;
    #pragma unroll
    for (int ct = 0; ct < 4; ++ct) {
        vfA[ct * 2 + 0] = *(const s8v*)(vfb + ct * 512);
        vfA[ct * 2 + 1] = *(const s8v*)(vfb + 8192 + ct * 512);
    }

#define TILE_BODY(TT, KF, VF, KFN, VFN, DOPF)                                     \
    {                                                                             \
        int p = (TT) & 1;                                                         \
        f4v S0 = {0.f, 0.f, 0.f, 0.f}, S1 = {0.f, 0.f, 0.f, 0.f};                 \
        S0 = __builtin_amdgcn_mfma_f32_16x16x32_bf16(Qf[0], KF, S0, 0, 0, 0);     \
        S1 = __builtin_amdgcn_mfma_f32_16x16x32_bf16(Qf[1], KF, S1, 0, 0, 0);     \
        _Pragma("unroll")                                                         \
        for (int r = 0; r < 4; ++r) {                                             \
            float e0 = __expf(fminf(S0[r], 60.f));                                \
            float e1 = __expf(fminf(S1[r], 60.f));                                \
            Lacc0[r] += e0; Lacc1[r] += e1;                                       \
            Ps[p][q * 4 + r][w * 16 + lm]      = f2u(e0);                         \
            Ps[p][16 + q * 4 + r][w * 16 + lm] = f2u(e1);                         \
        }                                                                         \
        __syncthreads();                                                          \
        if (DOPF) {                                                               \
            const ushort* vsrc = vfb + (size_t)((TT) + 1) * 16384;                \
            KFN = *(const s8v*)(kb + (size_t)((TT) + 1) * 2048);                  \
            _Pragma("unroll")                                                     \
            for (int ct = 0; ct < 4; ++ct) {                                      \
                VFN[ct * 2 + 0] = *(const s8v*)(vsrc + ct * 512);                 \
                VFN[ct * 2 + 1] = *(const s8v*)(vsrc + 8192 + ct * 512);          \
            }                                                                     \
        }                                                                         \
        s8v Af00 = *(const s8v*)&Ps[p][lm][q * 8];                                \
        s8v Af01 = *(const s8v*)&Ps[p][lm][32 + q * 8];                           \
        s8v Af10 = *(const s8v*)&Ps[p][16 + lm][q * 8];                           \
        s8v Af11 = *(const s8v*)&Ps[p][16 + lm][32 + q * 8];                      \
        _Pragma("unroll")                                                         \
        for (int ct = 0; ct < 4; ++ct) {                                          \
            acc0[ct] = __builtin_amdgcn_mfma_f32_16x16x32_bf16(Af00, VF[ct * 2 + 0], acc0[ct], 0, 0, 0); \
            acc1[ct] = __builtin_amdgcn_mfma_f32_16x16x32_bf16(Af10, VF[ct * 2 + 0], acc1[ct], 0, 0, 0); \
        }                                                                         \
        _Pragma("unroll")                                                         \
        for (int ct = 0; ct < 4; ++ct) {                                          \
            acc0[ct] = __builtin_amdgcn_mfma_f32_16x16x32_bf16(Af01, VF[ct * 2 + 1], acc0[ct], 0, 0, 0); \
            acc1[ct] = __builtin_amdgcn_mfma_f32_16x16x32_bf16(Af11, VF[ct * 2 + 1], acc1[ct], 0, 0, 0); \
        }                                                                         \
    }

    for (int t = 0; t < 64; t += 2) {
        TILE_BODY(t,     kfA, vfA, kfB, vfB, true);
        TILE_BODY(t + 1, kfB, vfB, kfA, vfA, (t + 2) < 64);
    }
#undef TILE_BODY

    // row sums: butterfly over the 16 strip-columns, then cross-wave add
    #pragma unroll
    for (int r = 0; r < 4; ++r) {
        float v0 = Lacc0[r], v1 = Lacc1[r];
        #pragma unroll
        for (int off = 1; off < 16; off <<= 1) {
            v0 += __shfl_xor(v0, off, 64);
            v1 += __shfl_xor(v1, off, 64);
        }
        Lacc0[r] = v0; Lacc1[r] = v1;
    }
    if (lm == 0) {
        #pragma unroll
        for (int r = 0; r < 4; ++r) {
            Lpart[w][q * 4 + r]      = Lacc0[r];
            Lpart[w][16 + q * 4 + r] = Lacc1[r];
        }
    }
    __syncthreads();
    if (tid < 32)
        Lrow[tid] = Lpart[0][tid] + Lpart[1][tid] + Lpart[2][tid] + Lpart[3][tid];
    __syncthreads();
    // epilogue: out = alpha*(acc/L) + (1-alpha)*x
    float alpha = alphap[0];
    float ra = 1.f - alpha;
    #pragma unroll
    for (int mt = 0; mt < 2; ++mt) {
        float L0 = Lrow[mt * 16 + q * 4 + 0];
        float L1 = Lrow[mt * 16 + q * 4 + 1];
        float L2 = Lrow[mt * 16 + q * 4 + 2];
        float L3 = Lrow[mt * 16 + q * 4 + 3];
        #pragma unroll
        for (int ct = 0; ct < 4; ++ct) {
            f4v a = mt ? acc1[ct] : acc0[ct];
            int cc = w * 64 + ct * 16 + lm;
            size_t base = ((size_t)(b * 256 + cc)) * 4096 + m0 + mt * 16 + q * 4;
            float4 xv = *(const float4*)(x + base);
            float4 ov;
            ov.x = alpha * (a[0] / L0) + ra * xv.x;
            ov.y = alpha * (a[1] / L1) + ra * xv.y;
            ov.z = alpha * (a[2] / L2) + ra * xv.z;
            ov.w = alpha * (a[3] / L3) + ra * xv.w;
            *(float4*)(out + base) = ov;
        }
    }
}

extern "C" void kernel_launch(void* const* d_in, const int* in_sizes, int n_in,
                              void* d_out, int out_size, void* d_ws, size_t ws_size,
                              hipStream_t stream) {
    const float* x  = (const float*)d_in[0];
    const float* wb = (const float*)d_in[1];
    const float* bb = (const float*)d_in[2];
    const float* wc = (const float*)d_in[3];
    const float* bc = (const float*)d_in[4];
    const float* wd = (const float*)d_in[5];
    const float* bd = (const float*)d_in[6];
    const float* al = (const float*)d_in[7];
    float* out = (float*)d_out;

    char* ws = (char*)d_ws;
    ushort* cat = (ushort*)ws;                    // 16 MiB
    ushort* Qb  = (ushort*)(ws + 16777216);       //  1 MiB
    ushort* Kb  = (ushort*)(ws + 17825792);       //  1 MiB
    ushort* Vf  = (ushort*)(ws + 18874368);       //  8 MiB (frag-ordered)

    pool_kernel<<<dim3(1024), dim3(256), 0, stream>>>(x, cat);
    proj_kernel<<<dim3(128, 5), dim3(256), 0, stream>>>(cat, wb, bb, wc, bc, wd, bd,
                                                        Qb, Kb, Vf);
    attn_kernel<<<dim3(512), dim3(256), 0, stream>>>(Qb, Kb, Vf, x, al, out);
}